// Round 27
// baseline (624.609 us; speedup 1.0000x reference)
//
#include <hip/hip_runtime.h>

#define M_DIM 8192
#define K_DIM 4096
#define N_DIM 16384
#define KT 32   // K tiles of 128

typedef __attribute__((ext_vector_type(4))) int i32x4;

__device__ __forceinline__ int pack4(int a, int b, int c, int d) {
  return (a & 255) | ((b & 255) << 8) | ((c & 255) << 16) | (d << 24);
}

// ---- pre-pass 1: x fp32 -> int8 per-row, sx[row] = rowmax/127 ------------
__global__ __launch_bounds__(256) void quant_x_kernel(const float* __restrict__ x,
    char* __restrict__ xq, float* __restrict__ sx) {
  const int row = blockIdx.x;
  const int tid = threadIdx.x;
  const float4* xr = reinterpret_cast<const float4*>(x + (size_t)row * K_DIM);
  float4 v[4];
  float m = 0.f;
#pragma unroll
  for (int j = 0; j < 4; ++j) {
    v[j] = xr[tid * 4 + j];
    m = fmaxf(m, fmaxf(fmaxf(fabsf(v[j].x), fabsf(v[j].y)),
                       fmaxf(fabsf(v[j].z), fabsf(v[j].w))));
  }
#pragma unroll
  for (int o = 32; o > 0; o >>= 1) m = fmaxf(m, __shfl_xor(m, o));
  __shared__ float wm[4];
  if ((tid & 63) == 0) wm[tid >> 6] = m;
  __syncthreads();
  m = fmaxf(fmaxf(wm[0], wm[1]), fmaxf(wm[2], wm[3]));
  const float r = (m > 0.f) ? 127.f / m : 0.f;
  i32x4 pk;
#pragma unroll
  for (int j = 0; j < 4; ++j)
    pk[j] = pack4((int)rintf(v[j].x * r), (int)rintf(v[j].y * r),
                  (int)rintf(v[j].z * r), (int)rintf(v[j].w * r));
  reinterpret_cast<i32x4*>(xq + (size_t)row * K_DIM)[tid] = pk;
  if (tid == 0) sx[row] = (m > 0.f) ? m / 127.f : 0.f;
}

// ---- pre-pass 2: w_q * blockscale -> per-ROW int8, sw[row] ---------------
__global__ __launch_bounds__(256) void requant_w_kernel(const int* __restrict__ wq,
    const float* __restrict__ wsc, char* __restrict__ w8, float* __restrict__ sw) {
  const int row = blockIdx.x;
  const int tid = threadIdx.x;
  const int4* q = reinterpret_cast<const int4*>(wq + (size_t)row * K_DIM);
  const float s = wsc[(row >> 7) * 32 + (tid >> 3)];
  int4 v[4];
  int mx = 0;
#pragma unroll
  for (int j = 0; j < 4; ++j) {
    v[j] = q[tid * 4 + j];
    mx = max(mx, max(max(abs(v[j].x), abs(v[j].y)), max(abs(v[j].z), abs(v[j].w))));
  }
  float fm = s * (float)mx;
#pragma unroll
  for (int o = 32; o > 0; o >>= 1) fm = fmaxf(fm, __shfl_xor(fm, o));
  __shared__ float wmx[4];
  if ((tid & 63) == 0) wmx[tid >> 6] = fm;
  __syncthreads();
  fm = fmaxf(fmaxf(wmx[0], wmx[1]), fmaxf(wmx[2], wmx[3]));
  const float swv = (fm > 0.f) ? fm / 127.f : 0.f;
  const float f = (fm > 0.f) ? s * (127.f / fm) : 0.f;
  if (tid == 0) sw[row] = swv;
  i32x4 pk;
#pragma unroll
  for (int j = 0; j < 4; ++j)
    pk[j] = pack4((int)rintf((float)v[j].x * f), (int)rintf((float)v[j].y * f),
                  (int)rintf((float)v[j].z * f), (int)rintf((float)v[j].w * f));
  reinterpret_cast<i32x4*>(w8 + (size_t)row * K_DIM)[tid] = pk;
}

// ---- async global -> LDS, 16 B per lane ----------------------------------
__device__ __forceinline__ void gload16(const void* g, void* l) {
  __builtin_amdgcn_global_load_lds(
      (const __attribute__((address_space(1))) unsigned int*)g,
      (__attribute__((address_space(3))) unsigned int*)l, 16, 0, 0);
}

#define BAR() do { asm volatile("" ::: "memory"); \
                   __builtin_amdgcn_s_barrier();  \
                   asm volatile("" ::: "memory"); } while (0)

#define MFI(a, b, c) __builtin_amdgcn_mfma_i32_16x16x64_i8(a, b, c, 0, 0, 0)

// ---- 256x256x128 8-wave pure-int8 GEMM, ONE barrier, reads-first ---------
// C = sx[row] * sw[col] * (Aq . Bq^T) + bias ; acc i32 exact over K=4096.
// Final structural variant: single barrier per tile (max de-phase window
// for the 2 waves sharing each SIMD) with CORRECT issue order (r25's flaw
// fixed): B-frags + A-bank0 ds_reads issue immediately post-barrier, the
// 8 STAGE_TILE VMEM issues follow, then the banked-A pipelined quad chain.
// End: vmcnt(0) (free - loads issued a full tile earlier) + BAR.
__global__ __launch_bounds__(512, 2) void gemm_kernel(
    const char* __restrict__ Aq, const char* __restrict__ Bq,
    const float* __restrict__ sw, const float* __restrict__ sx,
    const float* __restrict__ bias, float* __restrict__ C) {
  __shared__ __align__(128) char lds[131072];  // 2 bufs x (A 32K + B 32K)

  const int tid = threadIdx.x;
  const int lane = tid & 63, wid = tid >> 6;
  const int wr = wid >> 2, wc = wid & 3;    // 2 x 4 wave grid, 128x64/wave

  // Supertile ordering: 2048 blocks = 32(tm) x 64(tn); super = 16x16 tiles.
  const int bid = blockIdx.x;
  const int r = bid & 255;
  const int s = bid >> 8;                  // 0..7
  const int sm = s & 1, sn = s >> 1;       // 2 x 4 supers
  const int tm = sm * 16 + (r & 15);       // 0..31
  const int tn = sn * 16 + (r >> 4);       // 0..63

  // staging: per-lane pre-swizzled global source, linear LDS dest
  const int srow = (wid << 3) + (lane >> 3);
  const int kswz = ((lane & 7) ^ ((lane >> 3) & 7)) << 4;
  const char* aSrc = Aq + (size_t)(tm * 256 + srow) * K_DIM + kswz;
  const char* bSrc = Bq + (size_t)(tn * 256 + srow) * K_DIM + kswz;
  const int ldst = wid << 10;

#define STAGE_A(tt, h, s2, b) gload16(aSrc + (size_t)((h)*128 + (s2)*64) * K_DIM + (size_t)(tt)*128, \
                                      lds + (b)*65536 + (h)*16384 + (s2)*8192 + ldst)
#define STAGE_B(tt, h, s2, b) gload16(bSrc + (size_t)((h)*128 + (s2)*64) * K_DIM + (size_t)(tt)*128, \
                                      lds + (b)*65536 + 32768 + (h)*16384 + (s2)*8192 + ldst)
#define STAGE_TILE(tt, b) do { \
    STAGE_A(tt,0,0,b); STAGE_A(tt,0,1,b); STAGE_A(tt,1,0,b); STAGE_A(tt,1,1,b); \
    STAGE_B(tt,0,0,b); STAGE_B(tt,0,1,b); STAGE_B(tt,1,0,b); STAGE_B(tt,1,1,b); \
  } while (0)

  // fragment addressing (swizzled): 16B unit u stored at u^(row&7)
  const int hi = lane >> 4, lo3 = lane & 7;
  const int aks0 = ((0 + hi) ^ lo3) << 4;
  const int aks1 = ((4 + hi) ^ lo3) << 4;
  const int aoff = (wr * 128 + (lane & 15)) * 128;
  const int boff = 32768 + (wc * 64 + (lane & 15)) * 128;

  i32x4 acc[8][4] = {};
  i32x4 qa0, qa1, qa2, qa3;   // A bank A
  i32x4 qb0, qb1, qb2, qb3;   // A bank B

  // ---- prologue: stage tile 0 -> buf0 ------------------------------------
  STAGE_TILE(0, 0);
  asm volatile("s_waitcnt vmcnt(0)" ::: "memory");
  BAR();

#define RD_BANK(B0_, B1_, B2_, B3_, q) \
  B0_ = *(const i32x4*)(Ab + (2*(q)    ) * 2048 + aks0); \
  B1_ = *(const i32x4*)(Ab + (2*(q)    ) * 2048 + aks1); \
  B2_ = *(const i32x4*)(Ab + (2*(q) + 1) * 2048 + aks0); \
  B3_ = *(const i32x4*)(Ab + (2*(q) + 1) * 2048 + aks1);

#define QUADB(q, P0_, P1_, P2_, P3_) \
  acc[2*(q)][0]   = MFI(P0_, bf00, acc[2*(q)][0]); \
  acc[2*(q)][1]   = MFI(P0_, bf10, acc[2*(q)][1]); \
  acc[2*(q)][2]   = MFI(P0_, bf20, acc[2*(q)][2]); \
  acc[2*(q)][3]   = MFI(P0_, bf30, acc[2*(q)][3]); \
  acc[2*(q)+1][0] = MFI(P2_, bf00, acc[2*(q)+1][0]); \
  acc[2*(q)+1][1] = MFI(P2_, bf10, acc[2*(q)+1][1]); \
  acc[2*(q)+1][2] = MFI(P2_, bf20, acc[2*(q)+1][2]); \
  acc[2*(q)+1][3] = MFI(P2_, bf30, acc[2*(q)+1][3]); \
  acc[2*(q)][0]   = MFI(P1_, bf01, acc[2*(q)][0]); \
  acc[2*(q)][1]   = MFI(P1_, bf11, acc[2*(q)][1]); \
  acc[2*(q)][2]   = MFI(P1_, bf21, acc[2*(q)][2]); \
  acc[2*(q)][3]   = MFI(P1_, bf31, acc[2*(q)][3]); \
  acc[2*(q)+1][0] = MFI(P3_, bf01, acc[2*(q)+1][0]); \
  acc[2*(q)+1][1] = MFI(P3_, bf11, acc[2*(q)+1][1]); \
  acc[2*(q)+1][2] = MFI(P3_, bf21, acc[2*(q)+1][2]); \
  acc[2*(q)+1][3] = MFI(P3_, bf31, acc[2*(q)+1][3]);

  for (int t = 0; t < KT; ++t) {
    const int p = t & 1, pn = p ^ 1;
    const char* Ab = lds + p * 65536 + aoff;
    const char* Bb = lds + p * 65536 + boff;

    // reads FIRST: LDS pipe starts servicing immediately after the barrier
    const i32x4 bf00 = *(const i32x4*)(Bb + 0 * 2048 + aks0);
    const i32x4 bf01 = *(const i32x4*)(Bb + 0 * 2048 + aks1);
    const i32x4 bf10 = *(const i32x4*)(Bb + 1 * 2048 + aks0);
    const i32x4 bf11 = *(const i32x4*)(Bb + 1 * 2048 + aks1);
    const i32x4 bf20 = *(const i32x4*)(Bb + 2 * 2048 + aks0);
    const i32x4 bf21 = *(const i32x4*)(Bb + 2 * 2048 + aks1);
    const i32x4 bf30 = *(const i32x4*)(Bb + 3 * 2048 + aks0);
    const i32x4 bf31 = *(const i32x4*)(Bb + 3 * 2048 + aks1);
    RD_BANK(qa0, qa1, qa2, qa3, 0)

    // then the whole next tile's staging (targets buf pn, dead since t-1)
    if (t + 1 < KT) STAGE_TILE(t + 1, pn);

    // pipelined quads: next bank's reads issued before this bank's MFMAs
    RD_BANK(qb0, qb1, qb2, qb3, 1)
    QUADB(0, qa0, qa1, qa2, qa3)
    RD_BANK(qa0, qa1, qa2, qa3, 2)
    QUADB(1, qb0, qb1, qb2, qb3)
    RD_BANK(qb0, qb1, qb2, qb3, 3)
    QUADB(2, qa0, qa1, qa2, qa3)
    QUADB(3, qb0, qb1, qb2, qb3)

    // single sync point: next tile landed (issued a full tile ago)
    if (t + 1 < KT) {
      asm volatile("s_waitcnt vmcnt(0)" ::: "memory");
      BAR();
    }
  }

  // ---- epilogue: C = sx[row]*sw[col]*acc + bias; NT stores ---------------
  const int crow0 = tm * 256 + wr * 128 + ((lane >> 4) << 2);
  const int ccol0 = tn * 256 + wc * 64 + (lane & 15);
#pragma unroll
  for (int ni = 0; ni < 4; ++ni) {
    const float bv = bias[ccol0 + ni * 16];
    const float swc = sw[ccol0 + ni * 16];
#pragma unroll
    for (int mi = 0; mi < 8; ++mi) {
#pragma unroll
      for (int e = 0; e < 4; ++e) {
        const int row = crow0 + mi * 16 + e;
        __builtin_nontemporal_store(
            sx[row] * swc * (float)acc[mi][ni][e] + bv,
            &C[(size_t)row * N_DIM + ccol0 + ni * 16]);
      }
    }
  }
}

extern "C" void kernel_launch(void* const* d_in, const int* in_sizes, int n_in,
                              void* d_out, int out_size, void* d_ws, size_t ws_size,
                              hipStream_t stream) {
  const float* x    = (const float*)d_in[0];
  const int*   wq   = (const int*)d_in[1];
  const float* wsc  = (const float*)d_in[2];
  const float* bias = (const float*)d_in[3];
  float* out = (float*)d_out;

  const size_t xq_bytes = (size_t)M_DIM * K_DIM;        // 32 MB
  const size_t sx_bytes = (size_t)M_DIM * 4;            // 32 KB
  const size_t w8_bytes = (size_t)N_DIM * K_DIM;        // 64 MB
  const size_t sw_bytes = (size_t)N_DIM * 4;            // 64 KB
  if (ws_size < xq_bytes + sx_bytes + w8_bytes + sw_bytes) return;

  char*  xq  = (char*)d_ws;
  float* sxp = (float*)((char*)d_ws + xq_bytes);
  char*  w8  = (char*)d_ws + xq_bytes + sx_bytes;
  float* swp = (float*)((char*)d_ws + xq_bytes + sx_bytes + w8_bytes);

  quant_x_kernel<<<M_DIM, 256, 0, stream>>>(x, xq, sxp);
  requant_w_kernel<<<N_DIM, 256, 0, stream>>>(wq, wsc, w8, swp);
  gemm_kernel<<<(M_DIM / 256) * (N_DIM / 256), 512, 0, stream>>>(
      xq, w8, swp, sxp, bias, out);
}

// Round 28
// 601.859 us; speedup vs baseline: 1.0378x; 1.0378x over previous
//
#include <hip/hip_runtime.h>

#define M_DIM 8192
#define K_DIM 4096
#define N_DIM 16384
#define KT 32   // K tiles of 128

typedef __attribute__((ext_vector_type(4))) int i32x4;

__device__ __forceinline__ int pack4(int a, int b, int c, int d) {
  return (a & 255) | ((b & 255) << 8) | ((c & 255) << 16) | (d << 24);
}

// ---- pre-pass 1: x fp32 -> int8 per-row, sx[row] = rowmax/127 ------------
__global__ __launch_bounds__(256) void quant_x_kernel(const float* __restrict__ x,
    char* __restrict__ xq, float* __restrict__ sx) {
  const int row = blockIdx.x;
  const int tid = threadIdx.x;
  const float4* xr = reinterpret_cast<const float4*>(x + (size_t)row * K_DIM);
  float4 v[4];
  float m = 0.f;
#pragma unroll
  for (int j = 0; j < 4; ++j) {
    v[j] = xr[tid * 4 + j];
    m = fmaxf(m, fmaxf(fmaxf(fabsf(v[j].x), fabsf(v[j].y)),
                       fmaxf(fabsf(v[j].z), fabsf(v[j].w))));
  }
#pragma unroll
  for (int o = 32; o > 0; o >>= 1) m = fmaxf(m, __shfl_xor(m, o));
  __shared__ float wm[4];
  if ((tid & 63) == 0) wm[tid >> 6] = m;
  __syncthreads();
  m = fmaxf(fmaxf(wm[0], wm[1]), fmaxf(wm[2], wm[3]));
  const float r = (m > 0.f) ? 127.f / m : 0.f;
  i32x4 pk;
#pragma unroll
  for (int j = 0; j < 4; ++j)
    pk[j] = pack4((int)rintf(v[j].x * r), (int)rintf(v[j].y * r),
                  (int)rintf(v[j].z * r), (int)rintf(v[j].w * r));
  reinterpret_cast<i32x4*>(xq + (size_t)row * K_DIM)[tid] = pk;
  if (tid == 0) sx[row] = (m > 0.f) ? m / 127.f : 0.f;
}

// ---- pre-pass 2: w_q * blockscale -> per-ROW int8, sw[row] ---------------
__global__ __launch_bounds__(256) void requant_w_kernel(const int* __restrict__ wq,
    const float* __restrict__ wsc, char* __restrict__ w8, float* __restrict__ sw) {
  const int row = blockIdx.x;
  const int tid = threadIdx.x;
  const int4* q = reinterpret_cast<const int4*>(wq + (size_t)row * K_DIM);
  const float s = wsc[(row >> 7) * 32 + (tid >> 3)];
  int4 v[4];
  int mx = 0;
#pragma unroll
  for (int j = 0; j < 4; ++j) {
    v[j] = q[tid * 4 + j];
    mx = max(mx, max(max(abs(v[j].x), abs(v[j].y)), max(abs(v[j].z), abs(v[j].w))));
  }
  float fm = s * (float)mx;
#pragma unroll
  for (int o = 32; o > 0; o >>= 1) fm = fmaxf(fm, __shfl_xor(fm, o));
  __shared__ float wmx[4];
  if ((tid & 63) == 0) wmx[tid >> 6] = fm;
  __syncthreads();
  fm = fmaxf(fmaxf(wmx[0], wmx[1]), fmaxf(wmx[2], wmx[3]));
  const float swv = (fm > 0.f) ? fm / 127.f : 0.f;
  const float f = (fm > 0.f) ? s * (127.f / fm) : 0.f;
  if (tid == 0) sw[row] = swv;
  i32x4 pk;
#pragma unroll
  for (int j = 0; j < 4; ++j)
    pk[j] = pack4((int)rintf((float)v[j].x * f), (int)rintf((float)v[j].y * f),
                  (int)rintf((float)v[j].z * f), (int)rintf((float)v[j].w * f));
  reinterpret_cast<i32x4*>(w8 + (size_t)row * K_DIM)[tid] = pk;
}

// ---- async global -> LDS, 16 B per lane ----------------------------------
__device__ __forceinline__ void gload16(const void* g, void* l) {
  __builtin_amdgcn_global_load_lds(
      (const __attribute__((address_space(1))) unsigned int*)g,
      (__attribute__((address_space(3))) unsigned int*)l, 16, 0, 0);
}

#define BAR() do { asm volatile("" ::: "memory"); \
                   __builtin_amdgcn_s_barrier();  \
                   asm volatile("" ::: "memory"); } while (0)

#define MFI(a, b, c) __builtin_amdgcn_mfma_i32_16x16x64_i8(a, b, c, 0, 0, 0)

// ---- 256x256x128 8-wave pure-int8 GEMM, 2-barriers-per-tile (r24 best) ---
// C = sx[row] * sw[col] * (Aq . Bq^T) + bias ; acc i32 exact over K=4096.
// Session-best configuration (603 us total): per-row weight requant makes
// the K-loop pure int8 MFMA (no per-tile rescale VALU); 2 barriers/tile;
// no setprio (scheduling fence, hurts here); split A(t+1)-top / B(t+2)-mid
// staging; counted vmcnt(4); 16x16 supertile L3 blocking; NT C-stores.
// Plateau characterization: acc=128 AGPR -> 2 waves/SIMD, barrier-locked
// same-phase -> per-tile ~ LDS-service + MFMA (sum, not max); 7 structural
// variants (r22-r27) all land 530-560 us gemm, MfmaUtil 45-50%.
__global__ __launch_bounds__(512, 2) void gemm_kernel(
    const char* __restrict__ Aq, const char* __restrict__ Bq,
    const float* __restrict__ sw, const float* __restrict__ sx,
    const float* __restrict__ bias, float* __restrict__ C) {
  __shared__ __align__(128) char lds[131072];  // 2 bufs x (A 32K + B 32K)

  const int tid = threadIdx.x;
  const int lane = tid & 63, wid = tid >> 6;
  const int wr = wid >> 2, wc = wid & 3;    // 2 x 4 wave grid, 128x64/wave

  // Supertile ordering: 2048 blocks = 32(tm) x 64(tn); super = 16x16 tiles.
  const int bid = blockIdx.x;
  const int r = bid & 255;
  const int s = bid >> 8;                  // 0..7
  const int sm = s & 1, sn = s >> 1;       // 2 x 4 supers
  const int tm = sm * 16 + (r & 15);       // 0..31
  const int tn = sn * 16 + (r >> 4);       // 0..63

  // staging: per-lane pre-swizzled global source, linear LDS dest
  const int srow = (wid << 3) + (lane >> 3);
  const int kswz = ((lane & 7) ^ ((lane >> 3) & 7)) << 4;
  const char* aSrc = Aq + (size_t)(tm * 256 + srow) * K_DIM + kswz;
  const char* bSrc = Bq + (size_t)(tn * 256 + srow) * K_DIM + kswz;
  const int ldst = wid << 10;

#define STAGE_A(tt, h, s2, b) gload16(aSrc + (size_t)((h)*128 + (s2)*64) * K_DIM + (size_t)(tt)*128, \
                                      lds + (b)*65536 + (h)*16384 + (s2)*8192 + ldst)
#define STAGE_B(tt, h, s2, b) gload16(bSrc + (size_t)((h)*128 + (s2)*64) * K_DIM + (size_t)(tt)*128, \
                                      lds + (b)*65536 + 32768 + (h)*16384 + (s2)*8192 + ldst)
#define STAGE_A4(tt, b) do { STAGE_A(tt,0,0,b); STAGE_A(tt,0,1,b); STAGE_A(tt,1,0,b); STAGE_A(tt,1,1,b); } while (0)
#define STAGE_B4(tt, b) do { STAGE_B(tt,0,0,b); STAGE_B(tt,0,1,b); STAGE_B(tt,1,0,b); STAGE_B(tt,1,1,b); } while (0)

  // fragment addressing (swizzled): 16B unit u stored at u^(row&7)
  const int hi = lane >> 4, lo3 = lane & 7;
  const int aks0 = ((0 + hi) ^ lo3) << 4;
  const int aks1 = ((4 + hi) ^ lo3) << 4;
  const int aoff = (wr * 128 + (lane & 15)) * 128;
  const int boff = 32768 + (wc * 64 + (lane & 15)) * 128;

  i32x4 acc[8][4] = {};

  // ---- prologue: B0,A0 -> buf0; B1 -> buf1 -------------------------------
  STAGE_B4(0, 0);
  STAGE_A4(0, 0);
  STAGE_B4(1, 1);
  asm volatile("s_waitcnt vmcnt(4)" ::: "memory");  // tile 0 landed; B1 in flight
  BAR();

#define AFRAGS(q, P) \
  const i32x4 P##0 = *(const i32x4*)(Ab + (2*(q)    ) * 2048 + aks0); \
  const i32x4 P##1 = *(const i32x4*)(Ab + (2*(q)    ) * 2048 + aks1); \
  const i32x4 P##2 = *(const i32x4*)(Ab + (2*(q) + 1) * 2048 + aks0); \
  const i32x4 P##3 = *(const i32x4*)(Ab + (2*(q) + 1) * 2048 + aks1);

#define QUAD(q, P) \
  acc[2*(q)][0]   = MFI(P##0, bf00, acc[2*(q)][0]); \
  acc[2*(q)][1]   = MFI(P##0, bf10, acc[2*(q)][1]); \
  acc[2*(q)][2]   = MFI(P##0, bf20, acc[2*(q)][2]); \
  acc[2*(q)][3]   = MFI(P##0, bf30, acc[2*(q)][3]); \
  acc[2*(q)+1][0] = MFI(P##2, bf00, acc[2*(q)+1][0]); \
  acc[2*(q)+1][1] = MFI(P##2, bf10, acc[2*(q)+1][1]); \
  acc[2*(q)+1][2] = MFI(P##2, bf20, acc[2*(q)+1][2]); \
  acc[2*(q)+1][3] = MFI(P##2, bf30, acc[2*(q)+1][3]); \
  acc[2*(q)][0]   = MFI(P##1, bf01, acc[2*(q)][0]); \
  acc[2*(q)][1]   = MFI(P##1, bf11, acc[2*(q)][1]); \
  acc[2*(q)][2]   = MFI(P##1, bf21, acc[2*(q)][2]); \
  acc[2*(q)][3]   = MFI(P##1, bf31, acc[2*(q)][3]); \
  acc[2*(q)+1][0] = MFI(P##3, bf01, acc[2*(q)+1][0]); \
  acc[2*(q)+1][1] = MFI(P##3, bf11, acc[2*(q)+1][1]); \
  acc[2*(q)+1][2] = MFI(P##3, bf21, acc[2*(q)+1][2]); \
  acc[2*(q)+1][3] = MFI(P##3, bf31, acc[2*(q)+1][3]);

  for (int t = 0; t < KT; ++t) {
    const int p = t & 1, pn = p ^ 1;
    const char* Ab = lds + p * 65536 + aoff;
    const char* Bb = lds + p * 65536 + boff;

    // top: stage next tile's A into pn (pn A-region dead since t-1's end BAR)
    if (t + 1 < KT) STAGE_A4(t + 1, pn);

    // B fragments for this tile (8 ds_read_b128)
    const i32x4 bf00 = *(const i32x4*)(Bb + 0 * 2048 + aks0);
    const i32x4 bf01 = *(const i32x4*)(Bb + 0 * 2048 + aks1);
    const i32x4 bf10 = *(const i32x4*)(Bb + 1 * 2048 + aks0);
    const i32x4 bf11 = *(const i32x4*)(Bb + 1 * 2048 + aks1);
    const i32x4 bf20 = *(const i32x4*)(Bb + 2 * 2048 + aks0);
    const i32x4 bf21 = *(const i32x4*)(Bb + 2 * 2048 + aks1);
    const i32x4 bf30 = *(const i32x4*)(Bb + 3 * 2048 + aks0);
    const i32x4 bf31 = *(const i32x4*)(Bb + 3 * 2048 + aks1);

    // quads 0-1 (A reads inline; scheduler free to interleave)
    {
      AFRAGS(0, pa)
      QUAD(0, pa)
      AFRAGS(1, pb)
      QUAD(1, pb)
    }
    BAR();   // all waves' B-frag (and quad0/1 A) reads retired: B region dead
    if (t + 2 < KT) STAGE_B4(t + 2, p);

    // quads 2-3
    {
      AFRAGS(2, pc)
      QUAD(2, pc)
      AFRAGS(3, pd)
      QUAD(3, pd)
    }

    // end: drain {B(t+1), A(t+1)}; leave B(t+2) in flight
    if (t < KT - 2)       asm volatile("s_waitcnt vmcnt(4)" ::: "memory");
    else if (t == KT - 2) asm volatile("s_waitcnt vmcnt(0)" ::: "memory");
    if (t + 1 < KT) BAR();
  }

  // ---- epilogue: C = sx[row]*sw[col]*acc + bias; NT stores ---------------
  const int crow0 = tm * 256 + wr * 128 + ((lane >> 4) << 2);
  const int ccol0 = tn * 256 + wc * 64 + (lane & 15);
#pragma unroll
  for (int ni = 0; ni < 4; ++ni) {
    const float bv = bias[ccol0 + ni * 16];
    const float swc = sw[ccol0 + ni * 16];
#pragma unroll
    for (int mi = 0; mi < 8; ++mi) {
#pragma unroll
      for (int e = 0; e < 4; ++e) {
        const int row = crow0 + mi * 16 + e;
        __builtin_nontemporal_store(
            sx[row] * swc * (float)acc[mi][ni][e] + bv,
            &C[(size_t)row * N_DIM + ccol0 + ni * 16]);
      }
    }
  }
}

extern "C" void kernel_launch(void* const* d_in, const int* in_sizes, int n_in,
                              void* d_out, int out_size, void* d_ws, size_t ws_size,
                              hipStream_t stream) {
  const float* x    = (const float*)d_in[0];
  const int*   wq   = (const int*)d_in[1];
  const float* wsc  = (const float*)d_in[2];
  const float* bias = (const float*)d_in[3];
  float* out = (float*)d_out;

  const size_t xq_bytes = (size_t)M_DIM * K_DIM;        // 32 MB
  const size_t sx_bytes = (size_t)M_DIM * 4;            // 32 KB
  const size_t w8_bytes = (size_t)N_DIM * K_DIM;        // 64 MB
  const size_t sw_bytes = (size_t)N_DIM * 4;            // 64 KB
  if (ws_size < xq_bytes + sx_bytes + w8_bytes + sw_bytes) return;

  char*  xq  = (char*)d_ws;
  float* sxp = (float*)((char*)d_ws + xq_bytes);
  char*  w8  = (char*)d_ws + xq_bytes + sx_bytes;
  float* swp = (float*)((char*)d_ws + xq_bytes + sx_bytes + w8_bytes);

  quant_x_kernel<<<M_DIM, 256, 0, stream>>>(x, xq, sxp);
  requant_w_kernel<<<N_DIM, 256, 0, stream>>>(wq, wsc, w8, swp);
  gemm_kernel<<<(M_DIM / 256) * (N_DIM / 256), 512, 0, stream>>>(
      xq, w8, swp, sxp, bias, out);
}